// Round 2
// baseline (795.973 us; speedup 1.0000x reference)
//
#include <hip/hip_runtime.h>
#include <hip/hip_bf16.h>
#include <math.h>

#define U_N   8192
#define I_N   16384
#define D_N   64
#define OUT_N 64
#define BN    32           // items per iteration tile
#define NCH   8            // item chunks (split-K)
#define ITERS 64           // (I_N/NCH)/BN
#define VN_ST 72           // Vn stride (halves): 144B rows, b128 reads 2-way-free
#define VT_ST 40           // Vt stride (halves): 80B rows, b128-aligned, 2-way-free
#define PL_ST 40           // P round-trip stride (halves), 80B rows
#define AM_ST 68           // adj-mask LDS row stride (u32): 272B rows, 2-way-free

typedef _Float16 half8  __attribute__((ext_vector_type(8)));
typedef short    bf16x8 __attribute__((ext_vector_type(8)));
typedef short    bf16x4 __attribute__((ext_vector_type(4)));
typedef float    f32x4  __attribute__((ext_vector_type(4)));
typedef int      int4v  __attribute__((ext_vector_type(4)));

static __device__ __forceinline__ unsigned short f2bf(float f) {
    union { __hip_bfloat16 h; unsigned short u; } cv;
    cv.h = __float2bfloat16(f);
    return cv.u;
}
// Barrier WITHOUT vmcnt drain: LDS-only wait; global prefetches stay in flight.
static __device__ __forceinline__ void bar() {
    asm volatile("s_waitcnt lgkmcnt(0)\n\ts_barrier" ::: "memory");
}

// ---------------------------------------------------------------------------
// Prep: item_emb fp32 -> itemH f16 [item][dim] and itemTt bf16 tiled
// transpose [item>>5][dim][item&31] (staging becomes contiguous 16B copies).
// ---------------------------------------------------------------------------
__global__ __launch_bounds__(256)
void prep_items(const float* __restrict__ item,
                _Float16* __restrict__ itemH,
                unsigned short* __restrict__ itemTt)
{
    const int i = blockIdx.x * 256 + threadIdx.x;
    const float* src = item + (size_t)i * D_N;
    f32x4 v[16];
    #pragma unroll
    for (int j = 0; j < 16; ++j) v[j] = *(const f32x4*)(src + 4 * j);

    #pragma unroll
    for (int j = 0; j < 8; ++j) {
        half8 h;
        #pragma unroll
        for (int k = 0; k < 4; ++k) { h[k] = (_Float16)v[2*j][k]; h[4+k] = (_Float16)v[2*j+1][k]; }
        *(half8*)&itemH[(size_t)i * D_N + 8 * j] = h;
    }
    const size_t tb = (size_t)(i >> 5) * (D_N * 32) + (i & 31);
    #pragma unroll
    for (int d = 0; d < 64; ++d)
        itemTt[tb + (size_t)d * 32] = f2bf(v[d >> 2][d & 3]);
}

// ---------------------------------------------------------------------------
// Prep: adj int32 (0/1) -> bitmask, 1 bit/entry, row-major bits along i.
// Word wI covers items 32*wI..32*wI+31 of the flattened [U][I]; bit b of the
// u32 = (adj[32*wI + b] != 0)  (little-endian byte packing => bit order holds).
// Each thread packs 32 consecutive ints (128B contiguous read) -> fully
// streaming HBM access at fill bandwidth, unlike atten_main's old 128B-per-
// row-per-iter gather (49k concurrent streams -> DRAM page thrash, 1.6 TB/s).
// ---------------------------------------------------------------------------
__global__ __launch_bounds__(256)
void prep_adj(const int* __restrict__ adj, unsigned int* __restrict__ admask)
{
    const size_t nwords  = (size_t)U_N * I_N / 32;          // 4.19M u32
    const size_t gstride = (size_t)gridDim.x * 256;
    for (size_t wI = (size_t)blockIdx.x * 256 + threadIdx.x; wI < nwords; wI += gstride) {
        const int* p = adj + wI * 32;
        unsigned m = 0;
        #pragma unroll
        for (int j = 0; j < 8; ++j) {
            int4v a = *(const int4v*)(p + 4 * j);
            m |= (a[0] != 0 ? 1u : 0u) << (4 * j + 0);
            m |= (a[1] != 0 ? 1u : 0u) << (4 * j + 1);
            m |= (a[2] != 0 ? 1u : 0u) << (4 * j + 2);
            m |= (a[3] != 0 ? 1u : 0u) << (4 * j + 3);
        }
        admask[wI] = m;
    }
}

// ---------------------------------------------------------------------------
// Named-register pipeline state (arrays/structs/lambdas demote to scratch ->
// ~1 GB HBM scratch traffic; r3/r4 lesson).
// ---------------------------------------------------------------------------
#define DECL_SET(S) \
    half8 vn##S; bf16x8 vt##S;

#define LOAD_TILE(S, tidx) do { \
    const size_t o_ = (size_t)(tidx) * BN; \
    vn##S = *(const half8*)&itemH[(ibase0 + o_ + (t >> 3)) * D_N + (t & 7) * 8]; \
    vt##S = *(const bf16x8*)&itemTt[((ibase0 + o_) >> 5) * (D_N * 32) \
                                    + (size_t)(t >> 2) * 32 + (t & 3) * 8]; \
} while (0)

#define COMMIT(S, bufw) do { \
    *(half8*)&Vn[bufw][(t >> 3) * VN_ST + (t & 7) * 8] = vn##S; \
    *(bf16x8*)&Vt[bufw][(t >> 2) * VT_ST + (t & 3) * 8] = vt##S; \
} while (0)

// S^T = Item * User^T: A = item frags (Vn), B = ufrag. C-layout: lane (q,c)
// holds S^T[item=ig*16+4q+r][user=c] -> all 8 values belong to user row c.
#define COMPUTE_REST(ma, mb, bufr) do { \
    half8 a00 = *(const half8*)&Vn[bufr][(c)      * VN_ST      + q * 8]; \
    half8 a01 = *(const half8*)&Vn[bufr][(c)      * VN_ST + 32 + q * 8]; \
    half8 a10 = *(const half8*)&Vn[bufr][(16 + c) * VN_ST      + q * 8]; \
    half8 a11 = *(const half8*)&Vn[bufr][(16 + c) * VN_ST + 32 + q * 8]; \
    bf16x8 v0 = *(const bf16x8*)&Vt[bufr][(c)      * VT_ST + q * 8]; \
    bf16x8 v1 = *(const bf16x8*)&Vt[bufr][(16 + c) * VT_ST + q * 8]; \
    bf16x8 v2 = *(const bf16x8*)&Vt[bufr][(32 + c) * VT_ST + q * 8]; \
    bf16x8 v3 = *(const bf16x8*)&Vt[bufr][(48 + c) * VT_ST + q * 8]; \
    f32x4 T0 = (f32x4){0.f,0.f,0.f,0.f}; \
    f32x4 T1 = (f32x4){0.f,0.f,0.f,0.f}; \
    T0 = __builtin_amdgcn_mfma_f32_16x16x32_f16(a00, ufrag0, T0, 0, 0, 0); \
    T0 = __builtin_amdgcn_mfma_f32_16x16x32_f16(a01, ufrag1, T0, 0, 0, 0); \
    T1 = __builtin_amdgcn_mfma_f32_16x16x32_f16(a10, ufrag0, T1, 0, 0, 0); \
    T1 = __builtin_amdgcn_mfma_f32_16x16x32_f16(a11, ufrag1, T1, 0, 0, 0); \
    bf16x4 p0, p1; \
    float e_; \
    e_ = __expf(((ma) & 1u) ? T0[0] : 0.0f); p0[0] = (short)f2bf(e_); lc += e_; \
    e_ = __expf(((ma) & 2u) ? T0[1] : 0.0f); p0[1] = (short)f2bf(e_); lc += e_; \
    e_ = __expf(((ma) & 4u) ? T0[2] : 0.0f); p0[2] = (short)f2bf(e_); lc += e_; \
    e_ = __expf(((ma) & 8u) ? T0[3] : 0.0f); p0[3] = (short)f2bf(e_); lc += e_; \
    e_ = __expf(((mb) & 1u) ? T1[0] : 0.0f); p1[0] = (short)f2bf(e_); lc += e_; \
    e_ = __expf(((mb) & 2u) ? T1[1] : 0.0f); p1[1] = (short)f2bf(e_); lc += e_; \
    e_ = __expf(((mb) & 4u) ? T1[2] : 0.0f); p1[2] = (short)f2bf(e_); lc += e_; \
    e_ = __expf(((mb) & 8u) ? T1[3] : 0.0f); p1[3] = (short)f2bf(e_); lc += e_; \
    *(bf16x4*)&plw[c * PL_ST + 4 * q]      = p0; \
    *(bf16x4*)&plw[c * PL_ST + 16 + 4 * q] = p1; \
    bf16x8 pf = *(const bf16x8*)&plw[c * PL_ST + q * 8]; \
    O0 = __builtin_amdgcn_mfma_f32_16x16x32_bf16(pf, v0, O0, 0, 0, 0); \
    O1 = __builtin_amdgcn_mfma_f32_16x16x32_bf16(pf, v1, O1, 0, 0, 0); \
    O2 = __builtin_amdgcn_mfma_f32_16x16x32_bf16(pf, v2, O2, 0, 0, 0); \
    O3 = __builtin_amdgcn_mfma_f32_16x16x32_bf16(pf, v3, O3, 0, 0, 0); \
} while (0)

// ---------------------------------------------------------------------------
// Main: cooperative ping-pong LDS staging, one LDS-only barrier/iter, global
// prefetches in flight across barriers. Tile j: loaded j-3..j-2, committed
// j-1, consumed j. adj masks come from LDS (staged once, 16KB/block).
// ---------------------------------------------------------------------------
__global__ __launch_bounds__(256, 3)
void atten_main(const float* __restrict__ user_emb,
                const _Float16* __restrict__ itemH,
                const unsigned short* __restrict__ itemTt,
                const unsigned int* __restrict__ admask,
                float* __restrict__ wsO,
                float* __restrict__ wsL)
{
    __shared__ _Float16 Vn[2][BN * VN_ST];         // [item][dim] f16   (S^T A-frags)
    __shared__ short    Vt[2][D_N * VT_ST];        // [dim][item] bf16  (PV B-frags)
    __shared__ unsigned short Pl[4][16 * PL_ST];   // per-wave P round-trip
    __shared__ unsigned int   Msk[64 * AM_ST];     // adj bitmask: row r, word k

    const int ch   = blockIdx.x;
    const int ub   = blockIdx.y;
    const int t    = threadIdx.x;
    const int w    = t >> 6;
    const int lane = t & 63;
    const int c    = lane & 15;
    const int q    = lane >> 4;
    const int q4   = q << 2;

    const int    urow0  = ub * 64 + w * 16;
    const size_t ibase0 = (size_t)ch * (I_N / NCH);

    unsigned short* plw = &Pl[w][0];

    // persistent user fragments (f16); same registers serve as the MFMA
    // B-operand (B[k=ks*32+q*8+j][n=c]) for the transposed S matmul.
    half8 ufrag0, ufrag1;
    {
        const float* up = user_emb + (size_t)(urow0 + c) * D_N + q * 8;
        f32x4 a0 = *(const f32x4*)(up);
        f32x4 b0 = *(const f32x4*)(up + 4);
        f32x4 a1 = *(const f32x4*)(up + 32);
        f32x4 b1 = *(const f32x4*)(up + 36);
        #pragma unroll
        for (int j = 0; j < 4; ++j) {
            ufrag0[j] = (_Float16)a0[j]; ufrag0[4 + j] = (_Float16)b0[j];
            ufrag1[j] = (_Float16)a1[j]; ufrag1[4 + j] = (_Float16)b1[j];
        }
    }

    f32x4 O0 = (f32x4){0.f,0.f,0.f,0.f};
    f32x4 O1 = O0, O2 = O0, O3 = O0;
    float lc = 0.f;                       // softmax denom partial for user c

    // stage this block's adj-mask slice: 64 rows x 64 words (16KB), coalesced
    {
        const int r  = t >> 2;           // 0..63: block-local user row
        const int pt = t & 3;            // 0..3: 16-word segment
        const unsigned int* src = admask + (size_t)(ub * 64 + r) * (I_N / 32)
                                         + ch * (ITERS) + pt * 16;
        #pragma unroll
        for (int j = 0; j < 4; ++j)
            *(int4v*)&Msk[r * AM_ST + pt * 16 + 4 * j] = *(const int4v*)(src + 4 * j);
    }
    const unsigned int* mrow = &Msk[(w * 16 + c) * AM_ST];

    DECL_SET(A)
    DECL_SET(B)

    LOAD_TILE(A, 0);
    LOAD_TILE(B, 1);
    COMMIT(A, 0);
    LOAD_TILE(A, 2);
    bar();

    for (int k = 0; k < ITERS; k += 2) {
        {   // iter k: consume buf0; commit B->buf1; reload A-side
            const unsigned mw = mrow[k];
            const unsigned ma = (mw >> q4) & 0xFu;
            const unsigned mb = (mw >> (q4 + 16)) & 0xFu;
            COMMIT(B, 1);
            const int iv = (k + 3 < ITERS) ? k + 3 : ITERS - 1;
            LOAD_TILE(B, iv);
            COMPUTE_REST(ma, mb, 0);
            bar();
        }
        {   // iter k+1: consume buf1 + adjB; commit A->buf0; reload B-side
            const unsigned mw = mrow[k + 1];
            const unsigned ma = (mw >> q4) & 0xFu;
            const unsigned mb = (mw >> (q4 + 16)) & 0xFu;
            COMMIT(A, 0);
            const int iv = (k + 4 < ITERS) ? k + 4 : ITERS - 1;
            LOAD_TILE(A, iv);
            COMPUTE_REST(ma, mb, 1);
            bar();
        }
    }

    // l lives per-lane for user c: reduce across the 4 quads (lanes c+16q)
    lc += __shfl_xor(lc, 16);
    lc += __shfl_xor(lc, 32);

    // write chunk partials (O C-layout: lane (q,c): O[user 4q+r][dim 16nt+c])
    {
        float* d0 = wsO + ((size_t)ch * U_N + urow0 + 4 * q + 0) * D_N;
        float* d1 = wsO + ((size_t)ch * U_N + urow0 + 4 * q + 1) * D_N;
        float* d2 = wsO + ((size_t)ch * U_N + urow0 + 4 * q + 2) * D_N;
        float* d3 = wsO + ((size_t)ch * U_N + urow0 + 4 * q + 3) * D_N;
        d0[c] = O0[0]; d0[16 + c] = O1[0]; d0[32 + c] = O2[0]; d0[48 + c] = O3[0];
        d1[c] = O0[1]; d1[16 + c] = O1[1]; d1[32 + c] = O2[1]; d1[48 + c] = O3[1];
        d2[c] = O0[2]; d2[16 + c] = O1[2]; d2[32 + c] = O2[2]; d2[48 + c] = O3[2];
        d3[c] = O0[3]; d3[16 + c] = O1[3]; d3[32 + c] = O2[3]; d3[48 + c] = O3[3];
    }
    if (q == 0)
        wsL[(size_t)ch * U_N + urow0 + c] = lc;
}

// ---------------------------------------------------------------------------
// Combine: sum chunk partials, normalize, project by attention_weight.
// ---------------------------------------------------------------------------
__global__ __launch_bounds__(256)
void atten_combine(const float* __restrict__ wsO,
                   const float* __restrict__ wsL,
                   const float* __restrict__ attw,
                   float* __restrict__ out,
                   int nch)
{
    __shared__ float inv[64];
    __shared__ float agg[64][68];
    __shared__ float Wl[64][68];

    const int t  = threadIdx.x;
    const int u0 = blockIdx.x * 64;

    {
        const int d = t >> 2, o0 = (t & 3) * 16;
        const float* src = attw + d * OUT_N + o0;
        #pragma unroll
        for (int j = 0; j < 4; ++j)
            *(f32x4*)&Wl[d][o0 + 4 * j] = *(const f32x4*)(src + 4 * j);
    }
    if (t < 64) {
        float L = 0.f;
        for (int cc = 0; cc < nch; ++cc) L += wsL[(size_t)cc * U_N + u0 + t];
        inv[t] = 1.0f / L;
    }
    __syncthreads();

    {
        const int ul = t >> 2, d0 = (t & 3) * 16;
        const int u = u0 + ul;
        f32x4 a4[4];
        #pragma unroll
        for (int j = 0; j < 4; ++j) a4[j] = (f32x4){0.f, 0.f, 0.f, 0.f};
        for (int cc = 0; cc < nch; ++cc) {
            const float* src = wsO + ((size_t)cc * U_N + u) * D_N + d0;
            #pragma unroll
            for (int j = 0; j < 4; ++j) a4[j] += *(const f32x4*)(src + 4 * j);
        }
        const float s = inv[ul];
        #pragma unroll
        for (int j = 0; j < 4; ++j)
            *(f32x4*)&agg[ul][d0 + 4 * j] = a4[j] * s;
    }
    __syncthreads();

    {
        const int ul = t >> 2, o0 = (t & 3) * 16;
        f32x4 acc[4];
        #pragma unroll
        for (int j = 0; j < 4; ++j) acc[j] = (f32x4){0.f, 0.f, 0.f, 0.f};
        for (int d = 0; d < 64; ++d) {
            const float av = agg[ul][d];
            #pragma unroll
            for (int j = 0; j < 4; ++j) {
                f32x4 wv = *(const f32x4*)&Wl[d][o0 + 4 * j];
                acc[j] += wv * av;
            }
        }
        float* dst = out + (size_t)(u0 + ul) * OUT_N + o0;
        #pragma unroll
        for (int j = 0; j < 4; ++j)
            *(f32x4*)(dst + 4 * j) = acc[j];
    }
}

// ---------------------------------------------------------------------------
extern "C" void kernel_launch(void* const* d_in, const int* in_sizes, int n_in,
                              void* d_out, int out_size, void* d_ws, size_t ws_size,
                              hipStream_t stream)
{
    const float* user_emb = (const float*)d_in[0];
    const float* item_emb = (const float*)d_in[1];
    const float* attw     = (const float*)d_in[2];
    const int*   adj      = (const int*)d_in[3];
    float* out = (float*)d_out;

    // ws layout: wsO | wsL | itemH | itemTt | admask
    float*          wsO    = (float*)d_ws;
    float*          wsL    = wsO + (size_t)NCH * U_N * D_N;
    _Float16*       itemH  = (_Float16*)(wsL + (size_t)NCH * U_N);
    unsigned short* itemTt = (unsigned short*)(itemH + (size_t)I_N * D_N);
    unsigned int*   admask = (unsigned int*)(itemTt + (size_t)I_N * D_N);

    prep_items<<<dim3(I_N / 256), 256, 0, stream>>>(item_emb, itemH, itemTt);
    prep_adj<<<dim3(2048), 256, 0, stream>>>(adj, admask);
    atten_main<<<dim3(NCH, U_N / 64), 256, 0, stream>>>(user_emb, itemH, itemTt,
                                                        admask, wsO, wsL);
    atten_combine<<<dim3(U_N / 64), 256, 0, stream>>>(wsO, wsL, attw, out, NCH);
}

// Round 5
// 728.761 us; speedup vs baseline: 1.0922x; 1.0922x over previous
//
#include <hip/hip_runtime.h>
#include <hip/hip_bf16.h>
#include <math.h>

#define U_N   8192
#define I_N   16384
#define D_N   64
#define OUT_N 64
#define BN    32           // items per iteration tile
#define NCH   8            // item chunks (split-K)
#define ITERS 64           // (I_N/NCH)/BN
#define VN_ST 72           // Vn stride (halves): 144B rows, b128 reads 2-way-free
#define VT_ST 40           // Vt stride (halves): 80B rows, b128-aligned, 2-way-free
#define PL_ST 40           // P round-trip stride (halves), 80B rows

typedef _Float16 half8  __attribute__((ext_vector_type(8)));
typedef short    bf16x8 __attribute__((ext_vector_type(8)));
typedef short    bf16x4 __attribute__((ext_vector_type(4)));
typedef float    f32x4  __attribute__((ext_vector_type(4)));
typedef int      int4v  __attribute__((ext_vector_type(4)));

static __device__ __forceinline__ unsigned short f2bf(float f) {
    union { __hip_bfloat16 h; unsigned short u; } cv;
    cv.h = __float2bfloat16(f);
    return cv.u;
}
// Barrier WITHOUT vmcnt drain: LDS-only wait; global prefetches stay in flight.
static __device__ __forceinline__ void bar() {
    asm volatile("s_waitcnt lgkmcnt(0)\n\ts_barrier" ::: "memory");
}

// ---------------------------------------------------------------------------
// Prep: item_emb fp32 -> itemH f16 [item][dim] and itemTt bf16 tiled
// transpose [item>>5][dim][item&31] (staging becomes contiguous 16B copies).
// ---------------------------------------------------------------------------
__global__ __launch_bounds__(256)
void prep_items(const float* __restrict__ item,
                _Float16* __restrict__ itemH,
                unsigned short* __restrict__ itemTt)
{
    const int i = blockIdx.x * 256 + threadIdx.x;
    const float* src = item + (size_t)i * D_N;
    f32x4 v[16];
    #pragma unroll
    for (int j = 0; j < 16; ++j) v[j] = *(const f32x4*)(src + 4 * j);

    #pragma unroll
    for (int j = 0; j < 8; ++j) {
        half8 h;
        #pragma unroll
        for (int k = 0; k < 4; ++k) { h[k] = (_Float16)v[2*j][k]; h[4+k] = (_Float16)v[2*j+1][k]; }
        *(half8*)&itemH[(size_t)i * D_N + 8 * j] = h;
    }
    const size_t tb = (size_t)(i >> 5) * (D_N * 32) + (i & 31);
    #pragma unroll
    for (int d = 0; d < 64; ++d)
        itemTt[tb + (size_t)d * 32] = f2bf(v[d >> 2][d & 3]);
}

// ---------------------------------------------------------------------------
// Named-register pipeline state (arrays/structs/lambdas demote to scratch ->
// ~1 GB HBM scratch traffic; r3/r4 lesson).
// R3: adj visits widened to 256B/row (4x dwordx4 = masks for 2 iterations)
// and prefetch distance deepened to 3-4 iterations (~1400+ cy HBM cover).
// R2 lesson: adj reads were already near-peak + overlapped; bit-packing in a
// separate pass was strictly extra HBM traffic (+69 us). Burst width + depth
// inside the main loop is the only remaining adj lever.
// ---------------------------------------------------------------------------
#define DECL_SET(S) \
    int4v adj##S##a0, adj##S##b0, adj##S##a1, adj##S##b1; \
    half8 vn##S; bf16x8 vt##S;

// lane (q,c): adj row urow0+c; LOADW(kb) covers ints kb*32 .. kb*32+63
// (256B contiguous per row, = a/b masks for iters kb and kb+1)
#define LOAD_ADJW(S, kb) do { \
    const size_t o_ = (size_t)(kb) * BN; \
    adj##S##a0 = *(const int4v*)&adjq[o_];      \
    adj##S##b0 = *(const int4v*)&adjq[o_ + 16]; \
    adj##S##a1 = *(const int4v*)&adjq[o_ + 32]; \
    adj##S##b1 = *(const int4v*)&adjq[o_ + 48]; \
} while (0)

#define LOAD_TILE(S, tidx) do { \
    const size_t o_ = (size_t)(tidx) * BN; \
    vn##S = *(const half8*)&itemH[(ibase0 + o_ + (t >> 3)) * D_N + (t & 7) * 8]; \
    vt##S = *(const bf16x8*)&itemTt[((ibase0 + o_) >> 5) * (D_N * 32) \
                                    + (size_t)(t >> 2) * 32 + (t & 3) * 8]; \
} while (0)

#define COMMIT(S, bufw) do { \
    *(half8*)&Vn[bufw][(t >> 3) * VN_ST + (t & 7) * 8] = vn##S; \
    *(bf16x8*)&Vt[bufw][(t >> 2) * VT_ST + (t & 3) * 8] = vt##S; \
} while (0)

// per-lane 4-bit masks (extracted BEFORE the adj regs get reloaded)
#define MASKS0(S, ma, mb) \
    const unsigned ma = ((adj##S##a0[0] != 0) ? 1u : 0u) | ((adj##S##a0[1] != 0) ? 2u : 0u) | \
                        ((adj##S##a0[2] != 0) ? 4u : 0u) | ((adj##S##a0[3] != 0) ? 8u : 0u); \
    const unsigned mb = ((adj##S##b0[0] != 0) ? 1u : 0u) | ((adj##S##b0[1] != 0) ? 2u : 0u) | \
                        ((adj##S##b0[2] != 0) ? 4u : 0u) | ((adj##S##b0[3] != 0) ? 8u : 0u);
#define MASKS1(S, ma, mb) \
    const unsigned ma = ((adj##S##a1[0] != 0) ? 1u : 0u) | ((adj##S##a1[1] != 0) ? 2u : 0u) | \
                        ((adj##S##a1[2] != 0) ? 4u : 0u) | ((adj##S##a1[3] != 0) ? 8u : 0u); \
    const unsigned mb = ((adj##S##b1[0] != 0) ? 1u : 0u) | ((adj##S##b1[1] != 0) ? 2u : 0u) | \
                        ((adj##S##b1[2] != 0) ? 4u : 0u) | ((adj##S##b1[3] != 0) ? 8u : 0u);

// S^T = Item * User^T: A = item frags (Vn), B = ufrag. C-layout: lane (q,c)
// holds S^T[item=ig*16+4q+r][user=c] -> all 8 values belong to user row c.
#define COMPUTE_REST(ma, mb, bufr) do { \
    half8 a00 = *(const half8*)&Vn[bufr][(c)      * VN_ST      + q * 8]; \
    half8 a01 = *(const half8*)&Vn[bufr][(c)      * VN_ST + 32 + q * 8]; \
    half8 a10 = *(const half8*)&Vn[bufr][(16 + c) * VN_ST      + q * 8]; \
    half8 a11 = *(const half8*)&Vn[bufr][(16 + c) * VN_ST + 32 + q * 8]; \
    bf16x8 v0 = *(const bf16x8*)&Vt[bufr][(c)      * VT_ST + q * 8]; \
    bf16x8 v1 = *(const bf16x8*)&Vt[bufr][(16 + c) * VT_ST + q * 8]; \
    bf16x8 v2 = *(const bf16x8*)&Vt[bufr][(32 + c) * VT_ST + q * 8]; \
    bf16x8 v3 = *(const bf16x8*)&Vt[bufr][(48 + c) * VT_ST + q * 8]; \
    f32x4 T0 = (f32x4){0.f,0.f,0.f,0.f}; \
    f32x4 T1 = (f32x4){0.f,0.f,0.f,0.f}; \
    T0 = __builtin_amdgcn_mfma_f32_16x16x32_f16(a00, ufrag0, T0, 0, 0, 0); \
    T0 = __builtin_amdgcn_mfma_f32_16x16x32_f16(a01, ufrag1, T0, 0, 0, 0); \
    T1 = __builtin_amdgcn_mfma_f32_16x16x32_f16(a10, ufrag0, T1, 0, 0, 0); \
    T1 = __builtin_amdgcn_mfma_f32_16x16x32_f16(a11, ufrag1, T1, 0, 0, 0); \
    bf16x4 p0, p1; \
    float e_; \
    e_ = __expf(((ma) & 1u) ? T0[0] : 0.0f); p0[0] = (short)f2bf(e_); lc += e_; \
    e_ = __expf(((ma) & 2u) ? T0[1] : 0.0f); p0[1] = (short)f2bf(e_); lc += e_; \
    e_ = __expf(((ma) & 4u) ? T0[2] : 0.0f); p0[2] = (short)f2bf(e_); lc += e_; \
    e_ = __expf(((ma) & 8u) ? T0[3] : 0.0f); p0[3] = (short)f2bf(e_); lc += e_; \
    e_ = __expf(((mb) & 1u) ? T1[0] : 0.0f); p1[0] = (short)f2bf(e_); lc += e_; \
    e_ = __expf(((mb) & 2u) ? T1[1] : 0.0f); p1[1] = (short)f2bf(e_); lc += e_; \
    e_ = __expf(((mb) & 4u) ? T1[2] : 0.0f); p1[2] = (short)f2bf(e_); lc += e_; \
    e_ = __expf(((mb) & 8u) ? T1[3] : 0.0f); p1[3] = (short)f2bf(e_); lc += e_; \
    *(bf16x4*)&plw[c * PL_ST + 4 * q]      = p0; \
    *(bf16x4*)&plw[c * PL_ST + 16 + 4 * q] = p1; \
    bf16x8 pf = *(const bf16x8*)&plw[c * PL_ST + q * 8]; \
    O0 = __builtin_amdgcn_mfma_f32_16x16x32_bf16(pf, v0, O0, 0, 0, 0); \
    O1 = __builtin_amdgcn_mfma_f32_16x16x32_bf16(pf, v1, O1, 0, 0, 0); \
    O2 = __builtin_amdgcn_mfma_f32_16x16x32_bf16(pf, v2, O2, 0, 0, 0); \
    O3 = __builtin_amdgcn_mfma_f32_16x16x32_bf16(pf, v3, O3, 0, 0, 0); \
} while (0)

// ---------------------------------------------------------------------------
// Main: cooperative ping-pong LDS staging, one LDS-only barrier/iter, global
// prefetches in flight across barriers. Tile j: loaded j-3..j-2, committed
// j-1, consumed j. adj consumed from named regs, 256B bursts, dist-3/4.
// ---------------------------------------------------------------------------
__global__ __launch_bounds__(256, 3)
void atten_main(const float* __restrict__ user_emb,
                const _Float16* __restrict__ itemH,
                const unsigned short* __restrict__ itemTt,
                const int*   __restrict__ adj,
                float* __restrict__ wsO,
                float* __restrict__ wsL)
{
    __shared__ _Float16 Vn[2][BN * VN_ST];         // [item][dim] f16   (S^T A-frags)
    __shared__ short    Vt[2][D_N * VT_ST];        // [dim][item] bf16  (PV B-frags)
    __shared__ unsigned short Pl[4][16 * PL_ST];   // per-wave P round-trip

    const int ch   = blockIdx.x;
    const int ub   = blockIdx.y;
    const int t    = threadIdx.x;
    const int w    = t >> 6;
    const int lane = t & 63;
    const int c    = lane & 15;
    const int q    = lane >> 4;

    const int    urow0  = ub * 64 + w * 16;
    const size_t ibase0 = (size_t)ch * (I_N / NCH);

    unsigned short* plw = &Pl[w][0];

    // persistent user fragments (f16); same registers serve as the MFMA
    // B-operand (B[k=ks*32+q*8+j][n=c]) for the transposed S matmul.
    half8 ufrag0, ufrag1;
    {
        const float* up = user_emb + (size_t)(urow0 + c) * D_N + q * 8;
        f32x4 a0 = *(const f32x4*)(up);
        f32x4 b0 = *(const f32x4*)(up + 4);
        f32x4 a1 = *(const f32x4*)(up + 32);
        f32x4 b1 = *(const f32x4*)(up + 36);
        #pragma unroll
        for (int j = 0; j < 4; ++j) {
            ufrag0[j] = (_Float16)a0[j]; ufrag0[4 + j] = (_Float16)b0[j];
            ufrag1[j] = (_Float16)a1[j]; ufrag1[4 + j] = (_Float16)b1[j];
        }
    }

    f32x4 O0 = (f32x4){0.f,0.f,0.f,0.f};
    f32x4 O1 = O0, O2 = O0, O3 = O0;
    float lc = 0.f;                       // softmax denom partial for user c

    // adj base: row urow0+c, item offset 4q (dwordx4 covers items 4q..4q+3)
    const int* adjq = adj + (size_t)(urow0 + c) * I_N + ibase0 + 4 * q;

    DECL_SET(A)
    DECL_SET(B)

    LOAD_TILE(A, 0); LOAD_ADJW(A, 0);      // adj for iters 0,1
    LOAD_TILE(B, 1); LOAD_ADJW(B, 2);      // adj for iters 2,3
    COMMIT(A, 0);
    LOAD_TILE(A, 2);
    bar();

    for (int k = 0; k < ITERS; k += 4) {
        {   // iter k: consume buf0 + adjA part0; commit B->buf1
            MASKS0(A, ma, mb)
            COMMIT(B, 1);
            const int iv = (k + 3 < ITERS) ? k + 3 : ITERS - 1;
            LOAD_TILE(B, iv);
            COMPUTE_REST(ma, mb, 0);
            bar();
        }
        {   // iter k+1: consume buf1 + adjA part1; reload adjA (iters k+4,k+5)
            MASKS1(A, ma, mb)
            COMMIT(A, 0);
            const int ia = (k + 4 < ITERS) ? k + 4 : ITERS - 2;
            const int iv = (k + 4 < ITERS) ? k + 4 : ITERS - 1;
            LOAD_ADJW(A, ia);
            LOAD_TILE(A, iv);
            COMPUTE_REST(ma, mb, 1);
            bar();
        }
        {   // iter k+2: consume buf0 + adjB part0; commit B->buf1
            MASKS0(B, ma, mb)
            COMMIT(B, 1);
            const int iv = (k + 5 < ITERS) ? k + 5 : ITERS - 1;
            LOAD_TILE(B, iv);
            COMPUTE_REST(ma, mb, 0);
            bar();
        }
        {   // iter k+3: consume buf1 + adjB part1; reload adjB (iters k+6,k+7)
            MASKS1(B, ma, mb)
            COMMIT(A, 0);
            const int ia = (k + 6 < ITERS) ? k + 6 : ITERS - 2;
            const int iv = (k + 6 < ITERS) ? k + 6 : ITERS - 1;
            LOAD_ADJW(B, ia);
            LOAD_TILE(A, iv);
            COMPUTE_REST(ma, mb, 1);
            bar();
        }
    }

    // l lives per-lane for user c: reduce across the 4 quads (lanes c+16q)
    lc += __shfl_xor(lc, 16);
    lc += __shfl_xor(lc, 32);

    // write chunk partials (O C-layout: lane (q,c): O[user 4q+r][dim 16nt+c])
    {
        float* d0 = wsO + ((size_t)ch * U_N + urow0 + 4 * q + 0) * D_N;
        float* d1 = wsO + ((size_t)ch * U_N + urow0 + 4 * q + 1) * D_N;
        float* d2 = wsO + ((size_t)ch * U_N + urow0 + 4 * q + 2) * D_N;
        float* d3 = wsO + ((size_t)ch * U_N + urow0 + 4 * q + 3) * D_N;
        d0[c] = O0[0]; d0[16 + c] = O1[0]; d0[32 + c] = O2[0]; d0[48 + c] = O3[0];
        d1[c] = O0[1]; d1[16 + c] = O1[1]; d1[32 + c] = O2[1]; d1[48 + c] = O3[1];
        d2[c] = O0[2]; d2[16 + c] = O1[2]; d2[32 + c] = O2[2]; d2[48 + c] = O3[2];
        d3[c] = O0[3]; d3[16 + c] = O1[3]; d3[32 + c] = O2[3]; d3[48 + c] = O3[3];
    }
    if (q == 0)
        wsL[(size_t)ch * U_N + urow0 + c] = lc;
}

// ---------------------------------------------------------------------------
// Combine: sum chunk partials, normalize, project by attention_weight.
// ---------------------------------------------------------------------------
__global__ __launch_bounds__(256)
void atten_combine(const float* __restrict__ wsO,
                   const float* __restrict__ wsL,
                   const float* __restrict__ attw,
                   float* __restrict__ out,
                   int nch)
{
    __shared__ float inv[64];
    __shared__ float agg[64][68];
    __shared__ float Wl[64][68];

    const int t  = threadIdx.x;
    const int u0 = blockIdx.x * 64;

    {
        const int d = t >> 2, o0 = (t & 3) * 16;
        const float* src = attw + d * OUT_N + o0;
        #pragma unroll
        for (int j = 0; j < 4; ++j)
            *(f32x4*)&Wl[d][o0 + 4 * j] = *(const f32x4*)(src + 4 * j);
    }
    if (t < 64) {
        float L = 0.f;
        for (int cc = 0; cc < nch; ++cc) L += wsL[(size_t)cc * U_N + u0 + t];
        inv[t] = 1.0f / L;
    }
    __syncthreads();

    {
        const int ul = t >> 2, d0 = (t & 3) * 16;
        const int u = u0 + ul;
        f32x4 a4[4];
        #pragma unroll
        for (int j = 0; j < 4; ++j) a4[j] = (f32x4){0.f, 0.f, 0.f, 0.f};
        for (int cc = 0; cc < nch; ++cc) {
            const float* src = wsO + ((size_t)cc * U_N + u) * D_N + d0;
            #pragma unroll
            for (int j = 0; j < 4; ++j) a4[j] += *(const f32x4*)(src + 4 * j);
        }
        const float s = inv[ul];
        #pragma unroll
        for (int j = 0; j < 4; ++j)
            *(f32x4*)&agg[ul][d0 + 4 * j] = a4[j] * s;
    }
    __syncthreads();

    {
        const int ul = t >> 2, o0 = (t & 3) * 16;
        f32x4 acc[4];
        #pragma unroll
        for (int j = 0; j < 4; ++j) acc[j] = (f32x4){0.f, 0.f, 0.f, 0.f};
        for (int d = 0; d < 64; ++d) {
            const float av = agg[ul][d];
            #pragma unroll
            for (int j = 0; j < 4; ++j) {
                f32x4 wv = *(const f32x4*)&Wl[d][o0 + 4 * j];
                acc[j] += wv * av;
            }
        }
        float* dst = out + (size_t)(u0 + ul) * OUT_N + o0;
        #pragma unroll
        for (int j = 0; j < 4; ++j)
            *(f32x4*)(dst + 4 * j) = acc[j];
    }
}

// ---------------------------------------------------------------------------
extern "C" void kernel_launch(void* const* d_in, const int* in_sizes, int n_in,
                              void* d_out, int out_size, void* d_ws, size_t ws_size,
                              hipStream_t stream)
{
    const float* user_emb = (const float*)d_in[0];
    const float* item_emb = (const float*)d_in[1];
    const float* attw     = (const float*)d_in[2];
    const int*   adj      = (const int*)d_in[3];
    float* out = (float*)d_out;

    // ws layout: wsO | wsL | itemH | itemTt
    float*          wsO    = (float*)d_ws;
    float*          wsL    = wsO + (size_t)NCH * U_N * D_N;
    _Float16*       itemH  = (_Float16*)(wsL + (size_t)NCH * U_N);
    unsigned short* itemTt = (unsigned short*)(itemH + (size_t)I_N * D_N);

    prep_items<<<dim3(I_N / 256), 256, 0, stream>>>(item_emb, itemH, itemTt);
    atten_main<<<dim3(NCH, U_N / 64), 256, 0, stream>>>(user_emb, itemH, itemTt, adj,
                                                        wsO, wsL);
    atten_combine<<<dim3(U_N / 64), 256, 0, stream>>>(wsO, wsL, attw, out, NCH);
}